// Round 6
// baseline (1278.182 us; speedup 1.0000x reference)
//
#include <hip/hip_runtime.h>
#include <hip/hip_cooperative_groups.h>
#include <math.h>

namespace cg = cooperative_groups;

#define Nn 120000
#define Kk 8
#define Dd 64
#define Mm 100000
#define Pp 16
#define HGg 32
#define HDd 96
#define CAP 40   // per-voxel bucket capacity; actual max ~27-31
#define LUTB 12  // prefix bits for 2-level search (keys < 2^30)

typedef __attribute__((ext_vector_type(8))) short bf16x8;
typedef __attribute__((ext_vector_type(4))) float f32x4;
typedef __attribute__((ext_vector_type(4))) float fx4;   // nontemporal-load safe
typedef __attribute__((ext_vector_type(4))) int ix4;     // nontemporal-load safe

// prep block ranges (virtual blocks)
#define PB_K0    1563                 // ceil(Mm/64)
#define PB_PREP  (PB_K0 + 3750)       // Nn*Dd/8/256
#define PB_PACK  (PB_PREP + 22)       // ceil(86*64/256)
#define PB_INIT  (PB_PACK + 391)      // ceil(Mm/256)
#define NV_K1    (Nn / 32)            // 3750
#define NV_K2    (Mm / 4)             // 25000
#define NV_K3    ((Mm / 16 + 3) / 4)  // 1563
#define MEGA_GRID 1024                // 4 blocks/CU x 256 CU, co-resident

__device__ __forceinline__ float sigmoidf_(float x) { return 1.f / (1.f + __expf(-x)); }
__device__ __forceinline__ float tanh_fast(float x) {
    float e = __expf(2.f * x);
    return 1.f - 2.f / (e + 1.f);
}
// f32 -> bf16 round-to-nearest-even
__device__ __forceinline__ short f2bf(float f) {
    unsigned u = __float_as_uint(f);
    unsigned r = (u + 0x7fffu + ((u >> 16) & 1u)) >> 16;
    return (short)r;
}

// ===================== phase bodies (verbatim round-0/4 logic) =====================

__device__ __forceinline__ void prep_body(int b, int tid,
    const float* __restrict__ z, const float* __restrict__ Wz,
    const float* __restrict__ centers, const float* __restrict__ w_delta,
    const int* __restrict__ keys, const float* __restrict__ f_pts,
    const float* __restrict__ Wg1, const float* __restrict__ W_ih,
    const float* __restrict__ W_hh, const float* __restrict__ Wd1,
    const float* __restrict__ Wd2, const float* __restrict__ vals,
    unsigned* __restrict__ Zbf, float* __restrict__ cdot, int* __restrict__ lut,
    signed char* __restrict__ f8, short* __restrict__ wsW,
    int* __restrict__ cnt, float* __restrict__ vacc)
{
    if (b < PB_K0) {
        // ---- k0: 4 lanes/voxel proj + cdot + LUT ----
        int g = tid & 3;
        int m = b * 64 + (tid >> 2);
        if (m >= Mm) return;
        if (g == 0 && m <= (1 << LUTB)) {
            int target = m << (30 - LUTB);
            int lo = 0, hi = Mm;
            while (lo < hi) {
                int mid = (lo + hi) >> 1;
                if (keys[mid] < target) lo = mid + 1; else hi = mid;
            }
            lut[m] = lo;
        }
        const float4* zr = (const float4*)(z + (size_t)m * Dd + g * 16);
        float4 q0 = zr[0], q1 = zr[1], q2 = zr[2], q3 = zr[3];
        float acc[Pp];
#pragma unroll
        for (int p = 0; p < Pp; p++) {
            const float4* w = (const float4*)(Wz + (size_t)p * Dd + g * 16);
            float4 w0 = w[0], w1 = w[1], w2 = w[2], w3 = w[3];
            float s = q0.x * w0.x + q0.y * w0.y + q0.z * w0.z + q0.w * w0.w;
            s += q1.x * w1.x + q1.y * w1.y + q1.z * w1.z + q1.w * w1.w;
            s += q2.x * w2.x + q2.y * w2.y + q2.z * w2.z + q2.w * w2.w;
            s += q3.x * w3.x + q3.y * w3.y + q3.z * w3.z + q3.w * w3.w;
            acc[p] = s;
        }
#pragma unroll
        for (int p = 0; p < Pp; p++) {
            acc[p] += __shfl_xor(acc[p], 1, 64);
            acc[p] += __shfl_xor(acc[p], 2, 64);
        }
        float ss = 0.f;
#pragma unroll
        for (int p = 0; p < Pp; p++) ss = fmaf(acc[p], acc[p], ss);
        float inv = 1.f / (sqrtf(ss) + 1e-6f);
        unsigned* row = Zbf + (size_t)m * 8;         // 32 B row
        if (g < 2) {
            uint4 o;
            unsigned w[4];
#pragma unroll
            for (int j = 0; j < 4; j++) {
                float v0 = acc[g * 8 + 2 * j] * inv;
                float v1 = acc[g * 8 + 2 * j + 1] * inv;
                w[j] = (unsigned)(unsigned short)f2bf(v0)
                     | ((unsigned)(unsigned short)f2bf(v1) << 16);
            }
            o.x = w[0]; o.y = w[1]; o.z = w[2]; o.w = w[3];
            ((uint4*)row)[g] = o;
        } else if (g == 2) {
            cdot[m] = centers[3 * m] * w_delta[0] + centers[3 * m + 1] * w_delta[1]
                    + centers[3 * m + 2] * w_delta[2];
        }
    } else if (b < PB_PREP) {
        // ---- f_pts -> int8 (clamp +-4, x32), full 64 B rows ----
        int i = (b - PB_K0) * 256 + tid;             // 8 elems/thread
        int e = i * 8;
        const fx4* src = (const fx4*)(f_pts + e);
        fx4 a = __builtin_nontemporal_load(src);
        fx4 bb = __builtin_nontemporal_load(src + 1);
        float v[8] = {a.x, a.y, a.z, a.w, bb.x, bb.y, bb.z, bb.w};
        unsigned lo = 0, hi = 0;
#pragma unroll
        for (int j = 0; j < 4; j++) {
            int q = (int)rintf(fminf(fmaxf(v[j], -4.f), 4.f) * 32.f);
            lo |= ((unsigned)q & 0xffu) << (8 * j);
        }
#pragma unroll
        for (int j = 0; j < 4; j++) {
            int q = (int)rintf(fminf(fmaxf(v[4 + j], -4.f), 4.f) * 32.f);
            hi |= ((unsigned)q & 0xffu) << (8 * j);
        }
        *(int2*)(f8 + e) = make_int2((int)lo, (int)hi);
    } else if (b < PB_PACK) {
        // ---- weights -> bf16 MFMA B-fragment layout ----
        int idx = (b - PB_PREP) * 256 + tid;
        if (idx >= 86 * 64) return;
        int f = idx >> 6, lane = idx & 63;
        int lrow = lane & 15, lhi = lane >> 4;
        const float* src;
        int t, c, K;
        if (f < 8)       { int g = f;      t = g >> 2; c = g & 3;  src = Wg1;  K = 128; }
        else if (f < 32) { int g = f - 8;  t = g >> 1; c = g & 1;  src = W_ih; K = 64; }
        else if (f < 56) { int g = f - 32; t = g >> 1; c = g & 1;  src = W_hh; K = 64; }
        else if (f < 68) { int g = f - 56; t = g >> 1; c = g & 1;  src = Wd1;  K = 64; }
        else             { int g = f - 68; t = g / 3;  c = g % 3;  src = Wd2;  K = 96; }
        int o = t * 16 + lrow;
        int k0 = c * 32 + lhi * 8;
        short* dst = wsW + ((size_t)f * 64 + lane) * 8;
#pragma unroll
        for (int j = 0; j < 8; j++) dst[j] = f2bf(src[(size_t)o * K + k0 + j]);
    } else {
        // ---- init: cnt = 0, vacc = vals ----
        int m = (b - PB_PACK) * 256 + tid;
        if (m < Mm) {
            cnt[m] = 0;
            vacc[m] = vals[m];
        }
    }
}

__device__ __forceinline__ void k1_body(int vb, int tid,
    const float* __restrict__ pts, const float* __restrict__ f_pts,
    const float* __restrict__ Wf, const float* __restrict__ w_delta,
    const float* __restrict__ b_delta, const float* __restrict__ log_temp,
    const int* __restrict__ keys, const int* __restrict__ cand,
    const unsigned* __restrict__ Zbf, const float* __restrict__ cdot,
    const int* __restrict__ lut, float* __restrict__ vacc,
    int* __restrict__ cnt, int2* __restrict__ rec)
{
    int g = tid & 7;                          // lane-in-group (= candidate k)
    int n = vb * 32 + (tid >> 3);

    float px = pts[3 * n], py = pts[3 * n + 1], pz = pts[3 * n + 2];
    int myid = __builtin_nontemporal_load(cand + (size_t)n * Kk + g);

    if (g == 0) {
        // IEEE f32 divide then floor, matching the reference exactly
        int ix = (int)floorf(px / 0.1f);
        int iy = (int)floorf(py / 0.1f);
        int iz = (int)floorf(pz / 0.1f);
        int h = ((ix + 512) << 20) ^ ((iy + 512) << 10) ^ (iz + 512);
        int pfx = h >> (30 - LUTB);
        int lo = lut[pfx], hi = lut[pfx + 1];
        while (lo < hi) {
            int mid = (lo + hi) >> 1;
            if (keys[mid] < h) lo = mid + 1; else hi = mid;
        }
        int vi = lo < (Mm - 1) ? lo : (Mm - 1);
        atomicAdd(vacc + vi, 0.5f);
    }

    // ---- Fp partial dots over this lane's 8-float slice (nt stream) ----
    const fx4* fr = (const fx4*)(f_pts + (size_t)n * Dd + g * 8);
    fx4 q0 = __builtin_nontemporal_load(fr);
    fx4 q1 = __builtin_nontemporal_load(fr + 1);
    float fp[Pp];
#pragma unroll
    for (int p = 0; p < Pp; p++) {
        const float4* w = (const float4*)(Wf + (size_t)p * Dd + g * 8);
        float4 w0 = w[0], w1 = w[1];
        float s = q0.x * w0.x + q0.y * w0.y + q0.z * w0.z + q0.w * w0.w;
        s += q1.x * w1.x + q1.y * w1.y + q1.z * w1.z + q1.w * w1.w;
        fp[p] = s;
    }
#pragma unroll
    for (int p = 0; p < Pp; p++) {
        fp[p] += __shfl_xor(fp[p], 1, 64);
        fp[p] += __shfl_xor(fp[p], 2, 64);
        fp[p] += __shfl_xor(fp[p], 4, 64);
    }
    float ss = 0.f;
#pragma unroll
    for (int p = 0; p < Pp; p++) ss = fmaf(fp[p], fp[p], ss);
    float inv = 1.f / (sqrtf(ss) + 1e-6f);
#pragma unroll
    for (int p = 0; p < Pp; p++) fp[p] *= inv;

    float et = expf(log_temp[0]);
    float pdot = px * w_delta[0] + py * w_delta[1] + pz * w_delta[2] + b_delta[0];

    // ---- this lane's candidate: one 32 B row + one f32 ----
    const uint4* zp = (const uint4*)(Zbf + (size_t)myid * 8);
    uint4 A = zp[0], B = zp[1];
    float cd = cdot[myid];
    unsigned uw[8] = {A.x, A.y, A.z, A.w, B.x, B.y, B.z, B.w};
    float core = 0.f;
#pragma unroll
    for (int j = 0; j < 8; j++) {
        float lo = __uint_as_float(uw[j] << 16);
        float hi = __uint_as_float(uw[j] & 0xffff0000u);
        core = fmaf(fp[2 * j], lo, core);
        core = fmaf(fp[2 * j + 1], hi, core);
    }
    float sim = et * (core + pdot - cd) / 0.3f;

    // softmax over the 8 lanes of the group
    float mx = sim;
    mx = fmaxf(mx, __shfl_xor(mx, 1, 64));
    mx = fmaxf(mx, __shfl_xor(mx, 2, 64));
    mx = fmaxf(mx, __shfl_xor(mx, 4, 64));
    float e = __expf(sim - mx);
    float se = e;
    se += __shfl_xor(se, 1, 64);
    se += __shfl_xor(se, 2, 64);
    se += __shfl_xor(se, 4, 64);
    float w = e / se;

    // bucket insert: record = int2(n, w bits), one 8B nt store
    int pos = atomicAdd(cnt + myid, 1);
    if (pos < CAP) {
        long long pk = (unsigned)n | ((long long)(unsigned)__float_as_int(w) << 32);
        __builtin_nontemporal_store(pk, (long long*)(rec + (size_t)myid * CAP + pos));
    }
}

__device__ __forceinline__ void k2_body(int m, int lane,
    const signed char* __restrict__ f8, const int* __restrict__ cnt,
    const int2* __restrict__ rec, unsigned short* __restrict__ msgb)
{
    int c = cnt[m];
    if (c > CAP) c = CAP;
    const ix4* r4 = (const ix4*)(rec + (size_t)m * CAP);     // 2 records per ix4
    float acc = 0.f, wsum = 0.f;
    for (int i0 = 0; i0 < c; i0 += 8) {
        ix4 A = __builtin_nontemporal_load(r4 + (i0 >> 1) + 0);
        ix4 B = __builtin_nontemporal_load(r4 + (i0 >> 1) + 1);
        ix4 C = __builtin_nontemporal_load(r4 + (i0 >> 1) + 2);
        ix4 D = __builtin_nontemporal_load(r4 + (i0 >> 1) + 3);
        int nn[8];
        float ww[8];
        int rn[8] = {A.x, A.z, B.x, B.z, C.x, C.z, D.x, D.z};
        int rw[8] = {A.y, A.w, B.y, B.w, C.y, C.w, D.y, D.w};
#pragma unroll
        for (int k = 0; k < 8; k++) {
            bool valid = (i0 + k) < c;               // uniform -> scalar selects
            nn[k] = valid ? rn[k] : 0;               // clamp to safe row 0
            ww[k] = valid ? __int_as_float(rw[k]) : 0.f;
        }
        float vv[8];
#pragma unroll
        for (int k = 0; k < 8; k++)                  // 8 independent gathers
            vv[k] = (float)f8[((size_t)nn[k] << 6) + lane];
#pragma unroll
        for (int k = 0; k < 8; k++) {
            wsum += ww[k];
            acc = fmaf(ww[k], vv[k], acc);
        }
    }
    acc *= 0.03125f;
    msgb[(size_t)m * Dd + lane] = (unsigned short)f2bf(acc / (wsum + 1e-6f));
}

__device__ __forceinline__ void k3_body(int tile, int tid, float* scr,
    const float* __restrict__ z_latent, const unsigned short* __restrict__ msgb,
    const short* __restrict__ wsW, const float* __restrict__ bg1,
    const float* __restrict__ Wg2, const float* __restrict__ bg2,
    const float* __restrict__ b_ih, const float* __restrict__ b_hh,
    const float* __restrict__ ln_g, const float* __restrict__ ln_b,
    const float* __restrict__ bd1, const float* __restrict__ bd2,
    const float* __restrict__ Wd3, const float* __restrict__ bd3,
    const float* __restrict__ vacc, float* __restrict__ out)
{
    if (tile >= Mm / 16) return;             // no barriers below -> safe early exit
    int lane = tid & 63;
    int m0 = tile * 16;
    int lrow = lane & 15;
    int lhi = lane >> 4;

    if (lane < 16) {
        float v = vacc[m0 + lane];
        out[Mm + m0 + lane] = fminf(fmaxf(v, -2.f), 3.5f);
    }

    const bf16x8* WF = (const bf16x8*)wsW;
#define BFRAG(off) (WF[(off) * 64 + lane])

    bf16x8 za[2], ma[2];
    const float* zrow = z_latent + (size_t)(m0 + lrow) * Dd + lhi * 8;
    const bf16x8* mrow = (const bf16x8*)(msgb + (size_t)(m0 + lrow) * Dd + lhi * 8);
#pragma unroll
    for (int c = 0; c < 2; c++) {
        bf16x8 t0;
#pragma unroll
        for (int j = 0; j < 8; j++) t0[j] = f2bf(zrow[c * 32 + j]);
        za[c] = t0;
        ma[c] = mrow[c * 4];
    }

    // ---- gate ----
    bf16x8 wgf[8];
#pragma unroll
    for (int j = 0; j < 8; j++) wgf[j] = BFRAG(j);
    f32x4 g0 = {0.f, 0.f, 0.f, 0.f}, g1 = {0.f, 0.f, 0.f, 0.f};
    bf16x8 gateA[4] = {za[0], za[1], ma[0], ma[1]};
#pragma unroll
    for (int c = 0; c < 4; c++) {
        g0 = __builtin_amdgcn_mfma_f32_16x16x32_bf16(gateA[c], wgf[c], g0, 0, 0, 0);
        g1 = __builtin_amdgcn_mfma_f32_16x16x32_bf16(gateA[c], wgf[4 + c], g1, 0, 0, 0);
    }
    float bgA = bg1[lrow], bgB = bg1[16 + lrow];
    float w2A = Wg2[lrow], w2B = Wg2[16 + lrow];
    float g[4];
#pragma unroll
    for (int r = 0; r < 4; r++) {
        float ga = fmaxf(g0[r] + bgA, 0.f) * w2A + fmaxf(g1[r] + bgB, 0.f) * w2B;
        ga += __shfl_xor(ga, 1, 64);
        ga += __shfl_xor(ga, 2, 64);
        ga += __shfl_xor(ga, 4, 64);
        ga += __shfl_xor(ga, 8, 64);
        g[r] = sigmoidf_(ga + bg2[0]);
    }

    // ---- GRU ----
    float zn[4][4];
    float ps[4] = {0.f, 0.f, 0.f, 0.f}, pq[4] = {0.f, 0.f, 0.f, 0.f};
#pragma unroll
    for (int t = 0; t < 4; t++) {
        bf16x8 wt[12];
#pragma unroll
        for (int c = 0; c < 2; c++) {
            wt[0 + c]  = BFRAG(8 + t * 2 + c);
            wt[2 + c]  = BFRAG(8 + (t + 4) * 2 + c);
            wt[4 + c]  = BFRAG(8 + (t + 8) * 2 + c);
            wt[6 + c]  = BFRAG(32 + t * 2 + c);
            wt[8 + c]  = BFRAG(32 + (t + 4) * 2 + c);
            wt[10 + c] = BFRAG(32 + (t + 8) * 2 + c);
        }
        f32x4 Ar = {0.f, 0.f, 0.f, 0.f}, Az = Ar, An = Ar, Br = Ar, Bz = Ar, Bn = Ar;
#pragma unroll
        for (int c = 0; c < 2; c++) {
            Ar = __builtin_amdgcn_mfma_f32_16x16x32_bf16(ma[c], wt[0 + c], Ar, 0, 0, 0);
            Az = __builtin_amdgcn_mfma_f32_16x16x32_bf16(ma[c], wt[2 + c], Az, 0, 0, 0);
            An = __builtin_amdgcn_mfma_f32_16x16x32_bf16(ma[c], wt[4 + c], An, 0, 0, 0);
            Br = __builtin_amdgcn_mfma_f32_16x16x32_bf16(za[c], wt[6 + c], Br, 0, 0, 0);
            Bz = __builtin_amdgcn_mfma_f32_16x16x32_bf16(za[c], wt[8 + c], Bz, 0, 0, 0);
            Bn = __builtin_amdgcn_mfma_f32_16x16x32_bf16(za[c], wt[10 + c], Bn, 0, 0, 0);
        }
        int oc = t * 16 + lrow;
        float bir = b_ih[oc], biz = b_ih[64 + oc], bin = b_ih[128 + oc];
        float bhr = b_hh[oc], bhz = b_hh[64 + oc], bhn = b_hh[128 + oc];
#pragma unroll
        for (int r = 0; r < 4; r++) {
            int row = lhi * 4 + r;
            float zo = z_latent[(size_t)(m0 + row) * Dd + oc];
            float rr = sigmoidf_(Ar[r] + bir + Br[r] + bhr);
            float uu = sigmoidf_(Az[r] + biz + Bz[r] + bhz);
            float nnv = tanh_fast(An[r] + bin + rr * (Bn[r] + bhn));
            float hn = (1.f - uu) * nnv + uu * zo;
            float z2 = zo + g[r] * (hn - zo);
            zn[t][r] = z2;
            ps[r] += z2;
            pq[r] = fmaf(z2, z2, pq[r]);
        }
    }
    float mu[4], rs[4];
#pragma unroll
    for (int r = 0; r < 4; r++) {
        float s = ps[r], q = pq[r];
        s += __shfl_xor(s, 1, 64); q += __shfl_xor(q, 1, 64);
        s += __shfl_xor(s, 2, 64); q += __shfl_xor(q, 2, 64);
        s += __shfl_xor(s, 4, 64); q += __shfl_xor(q, 4, 64);
        s += __shfl_xor(s, 8, 64); q += __shfl_xor(q, 8, 64);
        float m = s * (1.f / 64.f);
        float v = q * (1.f / 64.f) - m * m;
        mu[r] = m;
        rs[r] = rsqrtf(v + 1e-5f);
    }
#pragma unroll
    for (int t = 0; t < 4; t++) {
        int o = t * 16 + lrow;
        float lg = ln_g[o], lb = ln_b[o];
#pragma unroll
        for (int r = 0; r < 4; r++)
            scr[(lhi * 4 + r) * 97 + o] = (zn[t][r] - mu[r]) * rs[r] * lg + lb;
    }
    __threadfence_block();

    bf16x8 xa[2];
#pragma unroll
    for (int c = 0; c < 2; c++) {
        bf16x8 tb;
#pragma unroll
        for (int j = 0; j < 8; j++) tb[j] = f2bf(scr[lrow * 97 + c * 32 + lhi * 8 + j]);
        xa[c] = tb;
    }
    bf16x8 wf1[12];
#pragma unroll
    for (int j = 0; j < 12; j++) wf1[j] = BFRAG(56 + j);
    f32x4 h1t[6];
#pragma unroll
    for (int t = 0; t < 6; t++) h1t[t] = (f32x4){0.f, 0.f, 0.f, 0.f};
#pragma unroll
    for (int t = 0; t < 6; t++)
#pragma unroll
        for (int c = 0; c < 2; c++)
            h1t[t] = __builtin_amdgcn_mfma_f32_16x16x32_bf16(xa[c], wf1[t * 2 + c], h1t[t], 0, 0, 0);
    float h1r[6][4];
#pragma unroll
    for (int t = 0; t < 6; t++) {
        float bb = bd1[t * 16 + lrow];
#pragma unroll
        for (int r = 0; r < 4; r++) {
            h1r[t][r] = fmaxf(h1t[t][r] + bb, 0.f);
            scr[(lhi * 4 + r) * 97 + t * 16 + lrow] = h1r[t][r];
        }
    }
    __threadfence_block();

    bf16x8 ha[3];
#pragma unroll
    for (int c = 0; c < 3; c++) {
        bf16x8 tb;
#pragma unroll
        for (int j = 0; j < 8; j++) tb[j] = f2bf(scr[lrow * 97 + c * 32 + lhi * 8 + j]);
        ha[c] = tb;
    }
    bf16x8 wf2[18];
#pragma unroll
    for (int j = 0; j < 18; j++) wf2[j] = BFRAG(68 + j);
    f32x4 o2[6];
#pragma unroll
    for (int t = 0; t < 6; t++) o2[t] = (f32x4){0.f, 0.f, 0.f, 0.f};
#pragma unroll
    for (int t = 0; t < 6; t++)
#pragma unroll
        for (int c = 0; c < 3; c++)
            o2[t] = __builtin_amdgcn_mfma_f32_16x16x32_bf16(ha[c], wf2[t * 3 + c], o2[t], 0, 0, 0);
    float pacc[4] = {0.f, 0.f, 0.f, 0.f};
#pragma unroll
    for (int t = 0; t < 6; t++) {
        int o = t * 16 + lrow;
        float bb = bd2[o], w3 = Wd3[o];
#pragma unroll
        for (int r = 0; r < 4; r++) {
            float hd2 = h1r[t][r] + fmaxf(o2[t][r] + bb, 0.f);
            pacc[r] = fmaf(hd2, w3, pacc[r]);
        }
    }
#pragma unroll
    for (int r = 0; r < 4; r++) {
        float s = pacc[r];
        s += __shfl_xor(s, 1, 64);
        s += __shfl_xor(s, 2, 64);
        s += __shfl_xor(s, 4, 64);
        s += __shfl_xor(s, 8, 64);
        if (lrow == 0) out[m0 + lhi * 4 + r] = sigmoidf_(s + bd3[0]);
    }
#undef BFRAG
}

// ===================== cooperative mega-kernel =====================
// 4 phases in one launch; >=43us of measured inter-kernel gap (strict bound
// from round-4 counters: prep/k2/k3 each <67.3 since top-5 is all k1, yet
// total-k1 = 245us) replaced by 3 grid.sync()s. Grid 1024 = 4 blocks/CU
// guaranteed co-resident by launch_bounds(256,4) (VGPR<=128, LDS 24.8KB).
// Phases with bad virtual/real block ratios (prep 5.6, k1 3.66, k3 1.53)
// use ticket counters with prefetch (atomic issued before the body so its
// latency hides under the work); k2 (ratio 24.4) is static grid-stride.
__global__ __launch_bounds__(256, 4) void mega(
    const float* __restrict__ pts, const float* __restrict__ f_pts,
    const float* __restrict__ z_lat, const float* __restrict__ vals,
    const float* __restrict__ centers, const float* __restrict__ Wf,
    const float* __restrict__ Wz, const float* __restrict__ w_delta,
    const float* __restrict__ b_delta, const float* __restrict__ log_temp,
    const float* __restrict__ W_ih, const float* __restrict__ W_hh,
    const float* __restrict__ b_ih, const float* __restrict__ b_hh,
    const float* __restrict__ Wg1, const float* __restrict__ bg1,
    const float* __restrict__ Wg2, const float* __restrict__ bg2,
    const float* __restrict__ ln_g, const float* __restrict__ ln_b,
    const float* __restrict__ Wd1, const float* __restrict__ bd1,
    const float* __restrict__ Wd2, const float* __restrict__ bd2,
    const float* __restrict__ Wd3, const float* __restrict__ bd3,
    const int* __restrict__ keys, const int* __restrict__ cand,
    float* __restrict__ out, float* ws)
{
    // ws-derived regions (must mirror host layout)
    short* wsW = (short*)ws;
    int* tick = (int*)(ws + 32000);             // 3 counters in wsW slack (host-zeroed)
    unsigned* Zbf = (unsigned*)(ws + 32768);
    float* cdot = ws + 32768 + 800000;
    signed char* f8 = (signed char*)(ws + 32768 + 900000);
    float* base = ws + 32768 + 900000 + 1920000;
    unsigned short* msgb = (unsigned short*)base;
    float* vacc = base + (size_t)Mm * Dd / 2;
    int* cnt = (int*)(vacc + Mm);
    int2* rec = (int2*)(cnt + Mm);
    int* lut = (int*)((int*)rec + (size_t)Mm * CAP * 2);

    cg::grid_group gg = cg::this_grid();
    __shared__ float scr_all[4][16 * 97];       // k3 wave-private stripes, 24.8 KB
    __shared__ int ls;
    int tid = threadIdx.x;
    int wv = tid >> 6, lane = tid & 63;

    // ---- phase 0: prep (ticketed, prefetch) ----
    if (tid == 0) ls = atomicAdd(&tick[0], 1);
    while (true) {
        __syncthreads();
        int vb = ls;
        __syncthreads();
        if (tid == 0) ls = atomicAdd(&tick[0], 1);
        if (vb >= PB_INIT) break;
        prep_body(vb, tid, z_lat, Wz, centers, w_delta, keys, f_pts,
                  Wg1, W_ih, W_hh, Wd1, Wd2, vals,
                  Zbf, cdot, lut, f8, wsW, cnt, vacc);
    }
    __threadfence();
    gg.sync();

    // ---- phase 1: k1 (ticketed, prefetch) ----
    if (tid == 0) ls = atomicAdd(&tick[1], 1);
    while (true) {
        __syncthreads();
        int vb = ls;
        __syncthreads();
        if (tid == 0) ls = atomicAdd(&tick[1], 1);
        if (vb >= NV_K1) break;
        k1_body(vb, tid, pts, f_pts, Wf, w_delta, b_delta, log_temp,
                keys, cand, Zbf, cdot, lut, vacc, cnt, rec);
    }
    __threadfence();
    gg.sync();

    // ---- phase 2: k2 (static grid-stride; ratio 24.4 -> 2.4% tail) ----
    for (int vb = blockIdx.x; vb < NV_K2; vb += MEGA_GRID)
        k2_body(vb * 4 + wv, lane, f8, cnt, rec, msgb);
    __threadfence();
    gg.sync();

    // ---- phase 3: k3 (ticketed; static would cost a 31% tail at ratio 1.53) ----
    if (tid == 0) ls = atomicAdd(&tick[2], 1);
    while (true) {
        __syncthreads();
        int vb = ls;
        __syncthreads();
        if (tid == 0) ls = atomicAdd(&tick[2], 1);
        if (vb >= NV_K3) break;
        k3_body(vb * 4 + wv, tid, scr_all[wv], z_lat, msgb, wsW, bg1, Wg2, bg2,
                b_ih, b_hh, ln_g, ln_b, bd1, bd2, Wd3, bd3, vacc, out);
    }
}

// ===================== fallback 4-kernel path (round-0 structure) =====================
__global__ __launch_bounds__(256) void k_prep_all(const float* __restrict__ z,
    const float* __restrict__ Wz, const float* __restrict__ centers,
    const float* __restrict__ w_delta, const int* __restrict__ keys,
    const float* __restrict__ f_pts, const float* __restrict__ Wg1,
    const float* __restrict__ W_ih, const float* __restrict__ W_hh,
    const float* __restrict__ Wd1, const float* __restrict__ Wd2,
    const float* __restrict__ vals, unsigned* __restrict__ Zbf,
    float* __restrict__ cdot, int* __restrict__ lut, signed char* __restrict__ f8,
    short* __restrict__ wsW, int* __restrict__ cnt, float* __restrict__ vacc)
{
    prep_body(blockIdx.x, threadIdx.x, z, Wz, centers, w_delta, keys, f_pts,
              Wg1, W_ih, W_hh, Wd1, Wd2, vals, Zbf, cdot, lut, f8, wsW, cnt, vacc);
}

__global__ __launch_bounds__(256) void k1_route(const float* __restrict__ pts,
    const float* __restrict__ f_pts, const float* __restrict__ Wf,
    const float* __restrict__ w_delta, const float* __restrict__ b_delta,
    const float* __restrict__ log_temp, const int* __restrict__ keys,
    const int* __restrict__ cand, const unsigned* __restrict__ Zbf,
    const float* __restrict__ cdot, const int* __restrict__ lut,
    float* __restrict__ vacc, int* __restrict__ cnt, int2* __restrict__ rec)
{
    k1_body(blockIdx.x, threadIdx.x, pts, f_pts, Wf, w_delta, b_delta, log_temp,
            keys, cand, Zbf, cdot, lut, vacc, cnt, rec);
}

__global__ __launch_bounds__(256) void k2_reduce(const signed char* __restrict__ f8,
    const int* __restrict__ cnt, const int2* __restrict__ rec,
    unsigned short* __restrict__ msgb)
{
    k2_body(blockIdx.x * 4 + (threadIdx.x >> 6), threadIdx.x & 63, f8, cnt, rec, msgb);
}

__global__ __launch_bounds__(256, 4) void k3_mfma(const float* __restrict__ z_latent,
    const unsigned short* __restrict__ msgb, const short* __restrict__ wsW,
    const float* __restrict__ bg1, const float* __restrict__ Wg2,
    const float* __restrict__ bg2, const float* __restrict__ b_ih,
    const float* __restrict__ b_hh, const float* __restrict__ ln_g,
    const float* __restrict__ ln_b, const float* __restrict__ bd1,
    const float* __restrict__ bd2, const float* __restrict__ Wd3,
    const float* __restrict__ bd3, const float* __restrict__ vacc,
    float* __restrict__ out)
{
    __shared__ float scr_all[4][16 * 97];
    int wv = threadIdx.x >> 6;
    k3_body(blockIdx.x * 4 + wv, threadIdx.x, scr_all[wv], z_latent, msgb, wsW,
            bg1, Wg2, bg2, b_ih, b_hh, ln_g, ln_b, bd1, bd2, Wd3, bd3, vacc, out);
}

extern "C" void kernel_launch(void* const* d_in, const int* in_sizes, int n_in,
                              void* d_out, int out_size, void* d_ws, size_t ws_size,
                              hipStream_t stream) {
    const float* pts      = (const float*)d_in[0];
    const float* f_pts    = (const float*)d_in[1];
    const float* z_lat    = (const float*)d_in[2];
    const float* vals     = (const float*)d_in[3];
    const float* centers  = (const float*)d_in[4];
    const float* Wf       = (const float*)d_in[5];
    const float* Wz       = (const float*)d_in[6];
    const float* w_delta  = (const float*)d_in[7];
    const float* b_delta  = (const float*)d_in[8];
    const float* log_temp = (const float*)d_in[9];
    const float* W_ih     = (const float*)d_in[10];
    const float* W_hh     = (const float*)d_in[11];
    const float* b_ih     = (const float*)d_in[12];
    const float* b_hh     = (const float*)d_in[13];
    const float* Wg1      = (const float*)d_in[14];
    const float* bg1      = (const float*)d_in[15];
    const float* Wg2      = (const float*)d_in[16];
    const float* bg2      = (const float*)d_in[17];
    const float* ln_g     = (const float*)d_in[18];
    const float* ln_b     = (const float*)d_in[19];
    const float* Wd1      = (const float*)d_in[20];
    const float* bd1      = (const float*)d_in[21];
    const float* Wd2      = (const float*)d_in[22];
    const float* bd2      = (const float*)d_in[23];
    const float* Wd3      = (const float*)d_in[24];
    const float* bd3      = (const float*)d_in[25];
    const int*   keys     = (const int*)d_in[26];
    const int*   cand     = (const int*)d_in[27];
    float* out = (float*)d_out;

    // ws layout — identical to round-0; tick counters live in the unused tail
    // of the wsW reservation (floats [22016, 32768) are slack; tick at 32000).
    float* ws = (float*)d_ws;
    short* wsW = (short*)ws;                                  // 88 KB used of 128 KB rsv
    unsigned* Zbf = (unsigned*)(ws + 32768);                  // M*8 uints (3.2 MB)
    float* cdot = ws + 32768 + 800000;                        // M floats (0.4 MB)
    signed char* f8 = (signed char*)(ws + 32768 + 900000);    // N*64 int8 (7.68 MB)
    float* base = ws + 32768 + 900000 + 1920000;
    unsigned short* msgb = (unsigned short*)base;             // M*64 bf16 (12.8 MB)
    float* vacc = base + (size_t)Mm * Dd / 2;                 // M
    int*   cnt  = (int*)(vacc + Mm);                          // M
    int2*  rec  = (int2*)(cnt + Mm);                          // M*CAP int2 (32 MB)
    int*   lut  = (int*)((int*)rec + (size_t)Mm * CAP * 2);   // 4097

    // zero the 3 ticket counters (12 B memset node; graph-capturable)
    hipMemsetAsync((void*)((char*)d_ws + 32000 * sizeof(float)), 0, 12, stream);

    float* wsf = (float*)d_ws;
    void* kargs[] = {&pts, &f_pts, &z_lat, &vals, &centers, &Wf, &Wz, &w_delta,
                     &b_delta, &log_temp, &W_ih, &W_hh, &b_ih, &b_hh, &Wg1, &bg1,
                     &Wg2, &bg2, &ln_g, &ln_b, &Wd1, &bd1, &Wd2, &bd2, &Wd3, &bd3,
                     &keys, &cand, &out, &wsf};
    hipError_t err = hipLaunchCooperativeKernel(mega, dim3(MEGA_GRID), dim3(256),
                                                kargs, 0u, stream);
    if (err != hipSuccess) {
        // fallback: proven 4-kernel round-0 path (identical bodies)
        k_prep_all<<<PB_INIT, 256, 0, stream>>>(z_lat, Wz, centers, w_delta, keys,
                                                f_pts, Wg1, W_ih, W_hh, Wd1, Wd2,
                                                vals, Zbf, cdot, lut, f8, wsW, cnt,
                                                vacc);
        k1_route<<<NV_K1, 256, 0, stream>>>(pts, f_pts, Wf, w_delta, b_delta,
                                            log_temp, keys, cand, Zbf, cdot, lut,
                                            vacc, cnt, rec);
        k2_reduce<<<NV_K2, 256, 0, stream>>>(f8, cnt, rec, msgb);
        k3_mfma<<<NV_K3, 256, 0, stream>>>(z_lat, msgb, wsW, bg1, Wg2, bg2, b_ih,
                                           b_hh, ln_g, ln_b, bd1, bd2, Wd3, bd3,
                                           vacc, out);
    }
}

// Round 7
// 279.043 us; speedup vs baseline: 4.5806x; 4.5806x over previous
//
#include <hip/hip_runtime.h>
#include <math.h>

#define Nn 120000
#define Kk 8
#define Dd 64
#define Mm 100000
#define Pp 16
#define HGg 32
#define HDd 96
#define CAP 40   // per-voxel bucket capacity; actual max ~27-31
#define LUTB 12  // prefix bits for 2-level search (keys < 2^30)

typedef __attribute__((ext_vector_type(8))) short bf16x8;
typedef __attribute__((ext_vector_type(4))) float f32x4;
typedef __attribute__((ext_vector_type(4))) float fx4;   // nontemporal-load safe
typedef __attribute__((ext_vector_type(4))) int ix4;     // nontemporal-load safe

// prep block ranges (f8 pack moved into k1; prep = k0 + weight pack + init)
#define PB_K0    1563                 // ceil(Mm/64)
#define PB_PACK  (PB_K0 + 22)        // ceil(86*64/256)
#define PB_INIT  (PB_PACK + 391)     // ceil(Mm/256)

__device__ __forceinline__ float sigmoidf_(float x) { return 1.f / (1.f + __expf(-x)); }
__device__ __forceinline__ float tanh_fast(float x) {
    float e = __expf(2.f * x);
    return 1.f - 2.f / (e + 1.f);
}
// f32 -> bf16 round-to-nearest-even
__device__ __forceinline__ short f2bf(float f) {
    unsigned u = __float_as_uint(f);
    unsigned r = (u + 0x7fffu + ((u >> 16) & 1u)) >> 16;
    return (short)r;
}

// ---- K_prep_all: k0 proj + weight pack + init (f8 pack now lives in k1) ----
__global__ __launch_bounds__(256) void k_prep_all(const float* __restrict__ z,
                                                  const float* __restrict__ Wz,
                                                  const float* __restrict__ centers,
                                                  const float* __restrict__ w_delta,
                                                  const int* __restrict__ keys,
                                                  const float* __restrict__ Wg1,
                                                  const float* __restrict__ W_ih,
                                                  const float* __restrict__ W_hh,
                                                  const float* __restrict__ Wd1,
                                                  const float* __restrict__ Wd2,
                                                  const float* __restrict__ vals,
                                                  unsigned* __restrict__ Zbf,
                                                  float* __restrict__ cdot,
                                                  int* __restrict__ lut,
                                                  short* __restrict__ wsW,
                                                  int* __restrict__ cnt,
                                                  float* __restrict__ vacc) {
    int b = blockIdx.x;
    if (b < PB_K0) {
        // ---- k0: 4 lanes/voxel proj + cdot + LUT ----
        int g = threadIdx.x & 3;
        int m = b * 64 + (threadIdx.x >> 2);
        if (m >= Mm) return;
        if (g == 0 && m <= (1 << LUTB)) {
            int target = m << (30 - LUTB);
            int lo = 0, hi = Mm;
            while (lo < hi) {
                int mid = (lo + hi) >> 1;
                if (keys[mid] < target) lo = mid + 1; else hi = mid;
            }
            lut[m] = lo;
        }
        const float4* zr = (const float4*)(z + (size_t)m * Dd + g * 16);
        float4 q0 = zr[0], q1 = zr[1], q2 = zr[2], q3 = zr[3];
        float acc[Pp];
#pragma unroll
        for (int p = 0; p < Pp; p++) {
            const float4* w = (const float4*)(Wz + (size_t)p * Dd + g * 16);
            float4 w0 = w[0], w1 = w[1], w2 = w[2], w3 = w[3];
            float s = q0.x * w0.x + q0.y * w0.y + q0.z * w0.z + q0.w * w0.w;
            s += q1.x * w1.x + q1.y * w1.y + q1.z * w1.z + q1.w * w1.w;
            s += q2.x * w2.x + q2.y * w2.y + q2.z * w2.z + q2.w * w2.w;
            s += q3.x * w3.x + q3.y * w3.y + q3.z * w3.z + q3.w * w3.w;
            acc[p] = s;
        }
#pragma unroll
        for (int p = 0; p < Pp; p++) {
            acc[p] += __shfl_xor(acc[p], 1, 64);
            acc[p] += __shfl_xor(acc[p], 2, 64);
        }
        float ss = 0.f;
#pragma unroll
        for (int p = 0; p < Pp; p++) ss = fmaf(acc[p], acc[p], ss);
        float inv = 1.f / (sqrtf(ss) + 1e-6f);
        unsigned* row = Zbf + (size_t)m * 8;         // 32 B row
        if (g < 2) {
            uint4 o;
            unsigned w[4];
#pragma unroll
            for (int j = 0; j < 4; j++) {
                float v0 = acc[g * 8 + 2 * j] * inv;
                float v1 = acc[g * 8 + 2 * j + 1] * inv;
                w[j] = (unsigned)(unsigned short)f2bf(v0)
                     | ((unsigned)(unsigned short)f2bf(v1) << 16);
            }
            o.x = w[0]; o.y = w[1]; o.z = w[2]; o.w = w[3];
            ((uint4*)row)[g] = o;
        } else if (g == 2) {
            cdot[m] = centers[3 * m] * w_delta[0] + centers[3 * m + 1] * w_delta[1]
                    + centers[3 * m + 2] * w_delta[2];
        }
    } else if (b < PB_PACK) {
        // ---- weights -> bf16 MFMA B-fragment layout ----
        int idx = (b - PB_K0) * 256 + threadIdx.x;
        if (idx >= 86 * 64) return;
        int f = idx >> 6, lane = idx & 63;
        int lrow = lane & 15, lhi = lane >> 4;
        const float* src;
        int t, c, K;
        if (f < 8)       { int g = f;      t = g >> 2; c = g & 3;  src = Wg1;  K = 128; }
        else if (f < 32) { int g = f - 8;  t = g >> 1; c = g & 1;  src = W_ih; K = 64; }
        else if (f < 56) { int g = f - 32; t = g >> 1; c = g & 1;  src = W_hh; K = 64; }
        else if (f < 68) { int g = f - 56; t = g >> 1; c = g & 1;  src = Wd1;  K = 64; }
        else             { int g = f - 68; t = g / 3;  c = g % 3;  src = Wd2;  K = 96; }
        int o = t * 16 + lrow;
        int k0 = c * 32 + lhi * 8;
        short* dst = wsW + ((size_t)f * 64 + lane) * 8;
#pragma unroll
        for (int j = 0; j < 8; j++) dst[j] = f2bf(src[(size_t)o * K + k0 + j]);
    } else {
        // ---- init: cnt = 0, vacc = vals ----
        int m = (b - PB_PACK) * 256 + threadIdx.x;
        if (m < Mm) {
            cnt[m] = 0;
            vacc[m] = vals[m];
        }
    }
}

// --- K1: 8 lanes/point. search on g==0; Fp via 8-way group dots;
//     1 candidate/lane. NOW ALSO packs f8 (int8 quantize) from the f_pts row
//     it already streams — deletes prep's separate 30.7MB f_pts pass. The
//     f8 store is coalesced (512B/wave) on a scattered-store-bound kernel:
//     +7.7MB of packed lines ~= +1-2us. Quantize expressions verbatim. -----
__global__ __launch_bounds__(256) void k1_route(const float* __restrict__ pts,
                                                const float* __restrict__ f_pts,
                                                const float* __restrict__ Wf,
                                                const float* __restrict__ w_delta,
                                                const float* __restrict__ b_delta,
                                                const float* __restrict__ log_temp,
                                                const int* __restrict__ keys,
                                                const int* __restrict__ cand,
                                                const unsigned* __restrict__ Zbf,
                                                const float* __restrict__ cdot,
                                                const int* __restrict__ lut,
                                                float* __restrict__ vacc,
                                                int* __restrict__ cnt,
                                                int2* __restrict__ rec,
                                                signed char* __restrict__ f8) {
    int g = threadIdx.x & 7;                         // lane-in-group (= candidate k)
    int n = blockIdx.x * 32 + (threadIdx.x >> 3);    // grid = 3750 exact

    float px = pts[3 * n], py = pts[3 * n + 1], pz = pts[3 * n + 2];
    int myid = __builtin_nontemporal_load(cand + (size_t)n * Kk + g);

    if (g == 0) {
        // IEEE f32 divide then floor, matching the reference exactly
        int ix = (int)floorf(px / 0.1f);
        int iy = (int)floorf(py / 0.1f);
        int iz = (int)floorf(pz / 0.1f);
        int h = ((ix + 512) << 20) ^ ((iy + 512) << 10) ^ (iz + 512);
        int pfx = h >> (30 - LUTB);
        int lo = lut[pfx], hi = lut[pfx + 1];
        while (lo < hi) {
            int mid = (lo + hi) >> 1;
            if (keys[mid] < h) lo = mid + 1; else hi = mid;
        }
        int vi = lo < (Mm - 1) ? lo : (Mm - 1);
        atomicAdd(vacc + vi, 0.5f);
    }

    // ---- Fp partial dots over this lane's 8-float slice (nt stream) ----
    const fx4* fr = (const fx4*)(f_pts + (size_t)n * Dd + g * 8);
    fx4 q0 = __builtin_nontemporal_load(fr);
    fx4 q1 = __builtin_nontemporal_load(fr + 1);

    // ---- f8 pack of this slice (verbatim quantize; coalesced int2 store) ----
    {
        float v[8] = {q0.x, q0.y, q0.z, q0.w, q1.x, q1.y, q1.z, q1.w};
        unsigned lo = 0, hi = 0;
#pragma unroll
        for (int j = 0; j < 4; j++) {
            int q = (int)rintf(fminf(fmaxf(v[j], -4.f), 4.f) * 32.f);
            lo |= ((unsigned)q & 0xffu) << (8 * j);
        }
#pragma unroll
        for (int j = 0; j < 4; j++) {
            int q = (int)rintf(fminf(fmaxf(v[4 + j], -4.f), 4.f) * 32.f);
            hi |= ((unsigned)q & 0xffu) << (8 * j);
        }
        *(int2*)(f8 + (size_t)n * Dd + g * 8) = make_int2((int)lo, (int)hi);
    }

    float fp[Pp];
#pragma unroll
    for (int p = 0; p < Pp; p++) {
        const float4* w = (const float4*)(Wf + (size_t)p * Dd + g * 8);
        float4 w0 = w[0], w1 = w[1];
        float s = q0.x * w0.x + q0.y * w0.y + q0.z * w0.z + q0.w * w0.w;
        s += q1.x * w1.x + q1.y * w1.y + q1.z * w1.z + q1.w * w1.w;
        fp[p] = s;
    }
#pragma unroll
    for (int p = 0; p < Pp; p++) {
        fp[p] += __shfl_xor(fp[p], 1, 64);
        fp[p] += __shfl_xor(fp[p], 2, 64);
        fp[p] += __shfl_xor(fp[p], 4, 64);
    }
    float ss = 0.f;
#pragma unroll
    for (int p = 0; p < Pp; p++) ss = fmaf(fp[p], fp[p], ss);
    float inv = 1.f / (sqrtf(ss) + 1e-6f);
#pragma unroll
    for (int p = 0; p < Pp; p++) fp[p] *= inv;

    float et = expf(log_temp[0]);
    float pdot = px * w_delta[0] + py * w_delta[1] + pz * w_delta[2] + b_delta[0];

    // ---- this lane's candidate: one 32 B row + one f32 ----
    const uint4* zp = (const uint4*)(Zbf + (size_t)myid * 8);
    uint4 A = zp[0], B = zp[1];
    float cd = cdot[myid];
    unsigned uw[8] = {A.x, A.y, A.z, A.w, B.x, B.y, B.z, B.w};
    float core = 0.f;
#pragma unroll
    for (int j = 0; j < 8; j++) {
        float lo = __uint_as_float(uw[j] << 16);
        float hi = __uint_as_float(uw[j] & 0xffff0000u);
        core = fmaf(fp[2 * j], lo, core);
        core = fmaf(fp[2 * j + 1], hi, core);
    }
    float sim = et * (core + pdot - cd) / 0.3f;

    // softmax over the 8 lanes of the group
    float mx = sim;
    mx = fmaxf(mx, __shfl_xor(mx, 1, 64));
    mx = fmaxf(mx, __shfl_xor(mx, 2, 64));
    mx = fmaxf(mx, __shfl_xor(mx, 4, 64));
    float e = __expf(sim - mx);
    float se = e;
    se += __shfl_xor(se, 1, 64);
    se += __shfl_xor(se, 2, 64);
    se += __shfl_xor(se, 4, 64);
    float w = e / se;

    // bucket insert: record = int2(n, w bits), one 8B nt store
    int pos = atomicAdd(cnt + myid, 1);
    if (pos < CAP) {
        long long pk = (unsigned)n | ((long long)(unsigned)__float_as_int(w) << 32);
        __builtin_nontemporal_store(pk, (long long*)(rec + (size_t)myid * CAP + pos));
    }
}

// ---- K23: fused gather-reduce + MFMA pipeline.
// Fusion done RIGHT this time (round-3 failed with 16 serial voxels/wave =
// ~64 dependent latency rounds): the k2 prologue is THREAD-per-voxel-quarter
// (64 voxels x 4 thr x 16 dims), so each thread owns ONE voxel with 8
// record-gathers in flight -> ~4 latency rounds, and block i's k3 compute
// overlaps block j's prologue gathers (4 blocks/CU). msg staged as bf16 in
// LDS [64][72] (pad -> <=2-way banks on the b128 fragment reads); deletes
// the standalone k2 dispatch (~45us) and the 25.6MB msgb HBM round trip.
// Per-dim accumulate keeps the exact k=0..c-1 fmaf chain -> bit-identical. --
__global__ __launch_bounds__(256, 4) void k23_mfma(const float* __restrict__ z_latent,
                                                   const signed char* __restrict__ f8,
                                                   const int* __restrict__ cnt,
                                                   const int2* __restrict__ rec,
                                                   const short* __restrict__ wsW,
                                                   const float* __restrict__ bg1,
                                                   const float* __restrict__ Wg2,
                                                   const float* __restrict__ bg2,
                                                   const float* __restrict__ b_ih,
                                                   const float* __restrict__ b_hh,
                                                   const float* __restrict__ ln_g,
                                                   const float* __restrict__ ln_b,
                                                   const float* __restrict__ bd1,
                                                   const float* __restrict__ bd2,
                                                   const float* __restrict__ Wd3,
                                                   const float* __restrict__ bd3,
                                                   const float* __restrict__ vacc,
                                                   float* __restrict__ out) {
    __shared__ unsigned short msgs[64][72];  // 9 KB bf16 msg tile (+8 pad)
    __shared__ float scr_all[4][16 * 97];    // wave-private 16x97 stripes, 24.8 KB
    int tid = threadIdx.x;
    int wv = tid >> 6, lane = tid & 63;
    int b = blockIdx.x;                      // grid = 1563

    // ---- fused k2 prologue: thread-per-voxel-quarter ----
    {
        int v = tid >> 2;                    // voxel within block, 0..63
        int dq = (tid & 3) << 4;             // dim quarter: 16 dims = 16 bytes
        int m = b * 64 + v;
        if (m < Mm) {
            int c = cnt[m];
            if (c > CAP) c = CAP;
            const ix4* r4 = (const ix4*)(rec + (size_t)m * CAP);  // plain loads:
            const signed char* fq = f8 + dq;  // L1 serves 4-thread duplicates
            float acc[16];
#pragma unroll
            for (int d = 0; d < 16; d++) acc[d] = 0.f;
            float wsum = 0.f;
            for (int i0 = 0; i0 < c; i0 += 8) {
                ix4 A = r4[(i0 >> 1) + 0];
                ix4 B = r4[(i0 >> 1) + 1];
                ix4 C = r4[(i0 >> 1) + 2];
                ix4 D = r4[(i0 >> 1) + 3];
                int rn[8] = {A.x, A.z, B.x, B.z, C.x, C.z, D.x, D.z};
                int rw[8] = {A.y, A.w, B.y, B.w, C.y, C.w, D.y, D.w};
                int nn[8];
                float ww[8];
#pragma unroll
                for (int k = 0; k < 8; k++) {
                    bool valid = (i0 + k) < c;
                    nn[k] = valid ? rn[k] : 0;           // clamp to safe row 0
                    ww[k] = valid ? __int_as_float(rw[k]) : 0.f;
                }
                int4 G[8];
#pragma unroll
                for (int k = 0; k < 8; k++)              // 8 x 16B gathers in flight
                    G[k] = *(const int4*)(fq + ((size_t)nn[k] << 6));
#pragma unroll
                for (int k = 0; k < 8; k++) {
                    wsum += ww[k];
                    int gg[4] = {G[k].x, G[k].y, G[k].z, G[k].w};
#pragma unroll
                    for (int q = 0; q < 4; q++)
#pragma unroll
                        for (int j = 0; j < 4; j++) {
                            float vv = (float)((signed char)((gg[q] >> (8 * j)) & 0xff));
                            acc[q * 4 + j] = fmaf(ww[k], vv, acc[q * 4 + j]);
                        }
                }
            }
#pragma unroll
            for (int d = 0; d < 16; d++) {
                float a = acc[d] * 0.03125f;
                msgs[v][dq + d] = (unsigned short)f2bf(a / (wsum + 1e-6f));
            }
        }
    }
    __syncthreads();

    // ---- k3 body (verbatim round-4; ma now read from LDS) ----
    int tile = b * 4 + wv;
    if (tile >= Mm / 16) return;             // after the only block-wide barrier
    int m0 = tile * 16;
    float* scr = scr_all[wv];
    int lrow = lane & 15;
    int lhi = lane >> 4;

    if (lane < 16) {
        float v = vacc[m0 + lane];
        out[Mm + m0 + lane] = fminf(fmaxf(v, -2.f), 3.5f);
    }

    const bf16x8* WF = (const bf16x8*)wsW;
#define BFRAG(off) (WF[(off) * 64 + lane])

    bf16x8 za[2], ma[2];
    const float* zrow = z_latent + (size_t)(m0 + lrow) * Dd + lhi * 8;
    const unsigned short* mr = &msgs[wv * 16 + lrow][lhi * 8];
#pragma unroll
    for (int c = 0; c < 2; c++) {
        bf16x8 t0;
#pragma unroll
        for (int j = 0; j < 8; j++) t0[j] = f2bf(zrow[c * 32 + j]);
        za[c] = t0;
        ma[c] = *(const bf16x8*)(mr + c * 32);
    }

    // ---- gate ----
    bf16x8 wgf[8];
#pragma unroll
    for (int j = 0; j < 8; j++) wgf[j] = BFRAG(j);
    f32x4 g0 = {0.f, 0.f, 0.f, 0.f}, g1 = {0.f, 0.f, 0.f, 0.f};
    bf16x8 gateA[4] = {za[0], za[1], ma[0], ma[1]};
#pragma unroll
    for (int c = 0; c < 4; c++) {
        g0 = __builtin_amdgcn_mfma_f32_16x16x32_bf16(gateA[c], wgf[c], g0, 0, 0, 0);
        g1 = __builtin_amdgcn_mfma_f32_16x16x32_bf16(gateA[c], wgf[4 + c], g1, 0, 0, 0);
    }
    float bgA = bg1[lrow], bgB = bg1[16 + lrow];
    float w2A = Wg2[lrow], w2B = Wg2[16 + lrow];
    float g[4];
#pragma unroll
    for (int r = 0; r < 4; r++) {
        float ga = fmaxf(g0[r] + bgA, 0.f) * w2A + fmaxf(g1[r] + bgB, 0.f) * w2B;
        ga += __shfl_xor(ga, 1, 64);
        ga += __shfl_xor(ga, 2, 64);
        ga += __shfl_xor(ga, 4, 64);
        ga += __shfl_xor(ga, 8, 64);
        g[r] = sigmoidf_(ga + bg2[0]);
    }

    // ---- GRU ----
    float zn[4][4];
    float ps[4] = {0.f, 0.f, 0.f, 0.f}, pq[4] = {0.f, 0.f, 0.f, 0.f};
#pragma unroll
    for (int t = 0; t < 4; t++) {
        bf16x8 wt[12];
#pragma unroll
        for (int c = 0; c < 2; c++) {
            wt[0 + c]  = BFRAG(8 + t * 2 + c);
            wt[2 + c]  = BFRAG(8 + (t + 4) * 2 + c);
            wt[4 + c]  = BFRAG(8 + (t + 8) * 2 + c);
            wt[6 + c]  = BFRAG(32 + t * 2 + c);
            wt[8 + c]  = BFRAG(32 + (t + 4) * 2 + c);
            wt[10 + c] = BFRAG(32 + (t + 8) * 2 + c);
        }
        f32x4 Ar = {0.f, 0.f, 0.f, 0.f}, Az = Ar, An = Ar, Br = Ar, Bz = Ar, Bn = Ar;
#pragma unroll
        for (int c = 0; c < 2; c++) {
            Ar = __builtin_amdgcn_mfma_f32_16x16x32_bf16(ma[c], wt[0 + c], Ar, 0, 0, 0);
            Az = __builtin_amdgcn_mfma_f32_16x16x32_bf16(ma[c], wt[2 + c], Az, 0, 0, 0);
            An = __builtin_amdgcn_mfma_f32_16x16x32_bf16(ma[c], wt[4 + c], An, 0, 0, 0);
            Br = __builtin_amdgcn_mfma_f32_16x16x32_bf16(za[c], wt[6 + c], Br, 0, 0, 0);
            Bz = __builtin_amdgcn_mfma_f32_16x16x32_bf16(za[c], wt[8 + c], Bz, 0, 0, 0);
            Bn = __builtin_amdgcn_mfma_f32_16x16x32_bf16(za[c], wt[10 + c], Bn, 0, 0, 0);
        }
        int oc = t * 16 + lrow;
        float bir = b_ih[oc], biz = b_ih[64 + oc], bin = b_ih[128 + oc];
        float bhr = b_hh[oc], bhz = b_hh[64 + oc], bhn = b_hh[128 + oc];
#pragma unroll
        for (int r = 0; r < 4; r++) {
            int row = lhi * 4 + r;
            float zo = z_latent[(size_t)(m0 + row) * Dd + oc];
            float rr = sigmoidf_(Ar[r] + bir + Br[r] + bhr);
            float uu = sigmoidf_(Az[r] + biz + Bz[r] + bhz);
            float nnv = tanh_fast(An[r] + bin + rr * (Bn[r] + bhn));
            float hn = (1.f - uu) * nnv + uu * zo;
            float z2 = zo + g[r] * (hn - zo);
            zn[t][r] = z2;
            ps[r] += z2;
            pq[r] = fmaf(z2, z2, pq[r]);
        }
    }
    float mu[4], rs[4];
#pragma unroll
    for (int r = 0; r < 4; r++) {
        float s = ps[r], q = pq[r];
        s += __shfl_xor(s, 1, 64); q += __shfl_xor(q, 1, 64);
        s += __shfl_xor(s, 2, 64); q += __shfl_xor(q, 2, 64);
        s += __shfl_xor(s, 4, 64); q += __shfl_xor(q, 4, 64);
        s += __shfl_xor(s, 8, 64); q += __shfl_xor(q, 8, 64);
        float m = s * (1.f / 64.f);
        float v = q * (1.f / 64.f) - m * m;
        mu[r] = m;
        rs[r] = rsqrtf(v + 1e-5f);
    }
#pragma unroll
    for (int t = 0; t < 4; t++) {
        int o = t * 16 + lrow;
        float lg = ln_g[o], lb = ln_b[o];
#pragma unroll
        for (int r = 0; r < 4; r++)
            scr[(lhi * 4 + r) * 97 + o] = (zn[t][r] - mu[r]) * rs[r] * lg + lb;
    }
    __threadfence_block();

    bf16x8 xa[2];
#pragma unroll
    for (int c = 0; c < 2; c++) {
        bf16x8 tb;
#pragma unroll
        for (int j = 0; j < 8; j++) tb[j] = f2bf(scr[lrow * 97 + c * 32 + lhi * 8 + j]);
        xa[c] = tb;
    }
    bf16x8 wf1[12];
#pragma unroll
    for (int j = 0; j < 12; j++) wf1[j] = BFRAG(56 + j);
    f32x4 h1t[6];
#pragma unroll
    for (int t = 0; t < 6; t++) h1t[t] = (f32x4){0.f, 0.f, 0.f, 0.f};
#pragma unroll
    for (int t = 0; t < 6; t++)
#pragma unroll
        for (int c = 0; c < 2; c++)
            h1t[t] = __builtin_amdgcn_mfma_f32_16x16x32_bf16(xa[c], wf1[t * 2 + c], h1t[t], 0, 0, 0);
    float h1r[6][4];
#pragma unroll
    for (int t = 0; t < 6; t++) {
        float bb = bd1[t * 16 + lrow];
#pragma unroll
        for (int r = 0; r < 4; r++) {
            h1r[t][r] = fmaxf(h1t[t][r] + bb, 0.f);
            scr[(lhi * 4 + r) * 97 + t * 16 + lrow] = h1r[t][r];
        }
    }
    __threadfence_block();

    bf16x8 ha[3];
#pragma unroll
    for (int c = 0; c < 3; c++) {
        bf16x8 tb;
#pragma unroll
        for (int j = 0; j < 8; j++) tb[j] = f2bf(scr[lrow * 97 + c * 32 + lhi * 8 + j]);
        ha[c] = tb;
    }
    bf16x8 wf2[18];
#pragma unroll
    for (int j = 0; j < 18; j++) wf2[j] = BFRAG(68 + j);
    f32x4 o2[6];
#pragma unroll
    for (int t = 0; t < 6; t++) o2[t] = (f32x4){0.f, 0.f, 0.f, 0.f};
#pragma unroll
    for (int t = 0; t < 6; t++)
#pragma unroll
        for (int c = 0; c < 3; c++)
            o2[t] = __builtin_amdgcn_mfma_f32_16x16x32_bf16(ha[c], wf2[t * 3 + c], o2[t], 0, 0, 0);
    float pacc[4] = {0.f, 0.f, 0.f, 0.f};
#pragma unroll
    for (int t = 0; t < 6; t++) {
        int o = t * 16 + lrow;
        float bb = bd2[o], w3 = Wd3[o];
#pragma unroll
        for (int r = 0; r < 4; r++) {
            float hd2 = h1r[t][r] + fmaxf(o2[t][r] + bb, 0.f);
            pacc[r] = fmaf(hd2, w3, pacc[r]);
        }
    }
#pragma unroll
    for (int r = 0; r < 4; r++) {
        float s = pacc[r];
        s += __shfl_xor(s, 1, 64);
        s += __shfl_xor(s, 2, 64);
        s += __shfl_xor(s, 4, 64);
        s += __shfl_xor(s, 8, 64);
        if (lrow == 0) out[m0 + lhi * 4 + r] = sigmoidf_(s + bd3[0]);
    }
#undef BFRAG
}

extern "C" void kernel_launch(void* const* d_in, const int* in_sizes, int n_in,
                              void* d_out, int out_size, void* d_ws, size_t ws_size,
                              hipStream_t stream) {
    const float* pts      = (const float*)d_in[0];
    const float* f_pts    = (const float*)d_in[1];
    const float* z_lat    = (const float*)d_in[2];
    const float* vals     = (const float*)d_in[3];
    const float* centers  = (const float*)d_in[4];
    const float* Wf       = (const float*)d_in[5];
    const float* Wz       = (const float*)d_in[6];
    const float* w_delta  = (const float*)d_in[7];
    const float* b_delta  = (const float*)d_in[8];
    const float* log_temp = (const float*)d_in[9];
    const float* W_ih     = (const float*)d_in[10];
    const float* W_hh     = (const float*)d_in[11];
    const float* b_ih     = (const float*)d_in[12];
    const float* b_hh     = (const float*)d_in[13];
    const float* Wg1      = (const float*)d_in[14];
    const float* bg1      = (const float*)d_in[15];
    const float* Wg2      = (const float*)d_in[16];
    const float* bg2      = (const float*)d_in[17];
    const float* ln_g     = (const float*)d_in[18];
    const float* ln_b     = (const float*)d_in[19];
    const float* Wd1      = (const float*)d_in[20];
    const float* bd1      = (const float*)d_in[21];
    const float* Wd2      = (const float*)d_in[22];
    const float* bd2      = (const float*)d_in[23];
    const float* Wd3      = (const float*)d_in[24];
    const float* bd3      = (const float*)d_in[25];
    const int*   keys     = (const int*)d_in[26];
    const int*   cand     = (const int*)d_in[27];
    float* out = (float*)d_out;

    // ws layout — identical offsets to round-0 (msgb region now unused).
    float* ws = (float*)d_ws;
    short* wsW = (short*)ws;                                  // 88 KB (32768 floats rsv)
    unsigned* Zbf = (unsigned*)(ws + 32768);                  // M*8 uints (3.2 MB)
    float* cdot = ws + 32768 + 800000;                        // M floats (0.4 MB)
    signed char* f8 = (signed char*)(ws + 32768 + 900000);    // N*64 int8 (7.68 MB)
    float* base = ws + 32768 + 900000 + 1920000;
    float* vacc = base + (size_t)Mm * Dd / 2;                 // M
    int*   cnt  = (int*)(vacc + Mm);                          // M
    int2*  rec  = (int2*)(cnt + Mm);                          // M*CAP int2 (32 MB)
    int*   lut  = (int*)((int*)rec + (size_t)Mm * CAP * 2);   // 4097

    k_prep_all<<<PB_INIT, 256, 0, stream>>>(z_lat, Wz, centers, w_delta, keys,
                                            Wg1, W_ih, W_hh, Wd1, Wd2, vals,
                                            Zbf, cdot, lut, wsW, cnt, vacc);
    k1_route<<<Nn / 32, 256, 0, stream>>>(pts, f_pts, Wf, w_delta, b_delta, log_temp,
                                          keys, cand, Zbf, cdot, lut, vacc, cnt, rec,
                                          f8);
    k23_mfma<<<(Mm / 16 + 3) / 4, 256, 0, stream>>>(z_lat, f8, cnt, rec, wsW, bg1,
                                                    Wg2, bg2, b_ih, b_hh, ln_g, ln_b,
                                                    bd1, bd2, Wd3, bd3, vacc, out);
}